// Round 6
// baseline (427.142 us; speedup 1.0000x reference)
//
#include <hip/hip_runtime.h>
#include <hip/hip_bf16.h>

#define DIM    1024
#define NH     16
#define DH     64
#define NSEQ   1605
#define HWIN   1600
#define PREFIX 5
#define NSEQP  1664   // 26*64, padded seq length for all head-major buffers

typedef __bf16 bf16_t;
typedef bf16_t bf16x8 __attribute__((ext_vector_type(8)));
typedef float  f32x4  __attribute__((ext_vector_type(4)));
typedef unsigned short u16;

#define MFMA(a,b,c) __builtin_amdgcn_mfma_f32_16x16x32_bf16(a,b,c,0,0,0)

union BU { bf16_t b; u16 u; };

struct Split8 { bf16x8 h, l; };
__device__ __forceinline__ Split8 split8(float4 a, float4 b) {
    Split8 r;
    float v[8] = {a.x, a.y, a.z, a.w, b.x, b.y, b.z, b.w};
#pragma unroll
    for (int i = 0; i < 8; ++i) {
        bf16_t hi = (bf16_t)v[i];
        r.h[i] = hi;
        r.l[i] = (bf16_t)(v[i] - (float)hi);
    }
    return r;
}

#define GSTR 40   // LDS k-stride in halves (80B): b128 reads/writes 2-way = free

// ===========================================================================
// GEMM 1: qkv = x @ W_qkv^T, split-3 bf16 MFMA. 128x128 tile, BK=32,
// 512 threads = 8 waves (4x2 of 32x64 wave tiles; 64-wide => full head per
// wave => RoPE partner d^32 = acc[rt][ct^2] in-lane). Double-buffered LDS,
// T14 split staging (load->regs early, LDS write late). Outputs:
// Q/K hi+lo bf16 [h][NSEQP][64] (RoPE+scale fused), V^T bf16 [h][64][NSEQP].
// ===========================================================================
__global__ __launch_bounds__(512) void gemm_qkv(
    const float* __restrict__ A, const float* __restrict__ B,
    const float* __restrict__ rope,
    bf16_t* __restrict__ Qhi, bf16_t* __restrict__ Qlo,
    bf16_t* __restrict__ Khi, bf16_t* __restrict__ Klo,
    bf16_t* __restrict__ Vt)
{
    __shared__ bf16_t Ah[2][128*GSTR], Al[2][128*GSTR];
    __shared__ bf16_t Bh[2][128*GSTR], Bl[2][128*GSTR];

    const int tid = threadIdx.x;
    const int m0 = blockIdx.y * 128, n0 = blockIdx.x * 128;
    const int w = tid >> 6, l = tid & 63, lr = l & 15, lg = l >> 4;
    const int wrow = (w >> 1) * 32;   // 0,32,64,96
    const int wcol = (w & 1) * 64;    // 0,64
    const int sr = tid >> 2;          // staging row 0..127
    const int sc = (tid & 3) * 8;     // staging col (halves/floats) 0,8,16,24

    const float* Arow = A + (size_t)(m0 + sr) * DIM + sc;
    const float* Brow = B + (size_t)(n0 + sr) * DIM + sc;
    const bool aok = (m0 + sr) < NSEQ;
    const float4 z4 = make_float4(0.f, 0.f, 0.f, 0.f);

    f32x4 acc[2][4] = {};
    float4 ra0, ra1, rb0, rb1;

#define LOADK(k0) do { \
        ra0 = aok ? *(const float4*)(Arow + (k0))     : z4; \
        ra1 = aok ? *(const float4*)(Arow + (k0) + 4) : z4; \
        rb0 = *(const float4*)(Brow + (k0)); \
        rb1 = *(const float4*)(Brow + (k0) + 4); } while (0)
#define STOREK(p) do { \
        Split8 sa = split8(ra0, ra1); \
        *(bf16x8*)&Ah[p][sr*GSTR + sc] = sa.h; \
        *(bf16x8*)&Al[p][sr*GSTR + sc] = sa.l; \
        Split8 sb = split8(rb0, rb1); \
        *(bf16x8*)&Bh[p][sr*GSTR + sc] = sb.h; \
        *(bf16x8*)&Bl[p][sr*GSTR + sc] = sb.l; } while (0)

    LOADK(0);
    STOREK(0);
    __syncthreads();

    int p = 0;
    for (int kt = 0; kt < 32; ++kt) {
        if (kt < 31) LOADK((kt + 1) * 32);     // issue next-tile global loads

        bf16x8 ah[2], al[2];
#pragma unroll
        for (int rt = 0; rt < 2; ++rt) {
            ah[rt] = *(const bf16x8*)&Ah[p][(wrow + 16*rt + lr)*GSTR + lg*8];
            al[rt] = *(const bf16x8*)&Al[p][(wrow + 16*rt + lr)*GSTR + lg*8];
        }
#pragma unroll
        for (int ct = 0; ct < 4; ++ct) {
            bf16x8 bh = *(const bf16x8*)&Bh[p][(wcol + 16*ct + lr)*GSTR + lg*8];
            bf16x8 bl = *(const bf16x8*)&Bl[p][(wcol + 16*ct + lr)*GSTR + lg*8];
#pragma unroll
            for (int rt = 0; rt < 2; ++rt) {
                acc[rt][ct] = MFMA(al[rt], bh, acc[rt][ct]);
                acc[rt][ct] = MFMA(ah[rt], bl, acc[rt][ct]);
                acc[rt][ct] = MFMA(ah[rt], bh, acc[rt][ct]);
            }
        }

        if (kt < 31) STOREK(p ^ 1);            // LDS write after compute
        __syncthreads();
        p ^= 1;
    }
#undef LOADK
#undef STOREK

    // ---- epilogue ----
    const int which = n0 >> 10;               // 0=Q 1=K 2=V
    const int cbase = (n0 & 1023) + wcol;
    const float qscale = (which == 0) ? 0.125f : 1.0f;
    const float* sinp = rope;
    const float* cosp = rope + (size_t)HWIN * DH;

#pragma unroll
    for (int ct = 0; ct < 4; ++ct) {
        const int col = cbase + 16 * ct + lr;
        const int hh = col >> 6, d = col & 63;
#pragma unroll
        for (int rt = 0; rt < 2; ++rt) {
            const int sbase = m0 + wrow + 16 * rt + 4 * lg;   // + reg
            if (sbase >= NSEQ) continue;
            if (which == 2) {
                // V^T: 4 consecutive seq at fixed d -> packed store
                size_t off = ((size_t)hh * DH + d) * NSEQP + sbase;
                if (sbase + 3 < NSEQ) {
                    BU t0, t1, t2, t3;
                    t0.b = (bf16_t)acc[rt][ct][0]; t1.b = (bf16_t)acc[rt][ct][1];
                    t2.b = (bf16_t)acc[rt][ct][2]; t3.b = (bf16_t)acc[rt][ct][3];
                    ushort4 pk = make_ushort4(t0.u, t1.u, t2.u, t3.u);
                    *(ushort4*)((u16*)Vt + off) = pk;
                } else {
#pragma unroll
                    for (int reg = 0; reg < 4; ++reg)
                        if (sbase + reg < NSEQ)
                            Vt[off + reg] = (bf16_t)acc[rt][ct][reg];
                }
            } else {
#pragma unroll
                for (int reg = 0; reg < 4; ++reg) {
                    const int seq = sbase + reg;
                    if (seq >= NSEQ) continue;
                    float val = acc[rt][ct][reg] * qscale;
                    float o = val;
                    if (seq >= PREFIX) {
                        float partner = acc[rt][ct ^ 2][reg] * qscale;
                        float rot = (d < 32) ? -partner : partner;
                        float sn = sinp[(size_t)(seq - PREFIX) * DH + d];
                        float cs = cosp[(size_t)(seq - PREFIX) * DH + d];
                        o = val * cs + rot * sn;
                    }
                    bf16_t hh2 = (bf16_t)o;
                    bf16_t ll2 = (bf16_t)(o - (float)hh2);
                    size_t off = ((size_t)hh * NSEQP + seq) * DH + d;
                    if (which == 0) { Qhi[off] = hh2; Qlo[off] = ll2; }
                    else            { Khi[off] = hh2; Klo[off] = ll2; }
                }
            }
        }
    }
}

// ===========================================================================
// Flash attention, barrier-free. Block = (head, 64-q tile), 4 independent
// waves of 16 q rows. Q hi/lo in regs; K/V MFMA B-frags loaded DIRECT from
// global (b128, L1/L2-served; buffers padded to NSEQP so no guards);
// P does a wave-private LDS round-trip (no __syncthreads anywhere).
// ===========================================================================
#define ASTRH 72

__global__ __launch_bounds__(256) void attn_kernel(
    const bf16_t* __restrict__ Qhi, const bf16_t* __restrict__ Qlo,
    const bf16_t* __restrict__ Khi, const bf16_t* __restrict__ Klo,
    const bf16_t* __restrict__ Vt, float* __restrict__ O)
{
    __shared__ bf16_t PS[4][16 * ASTRH];

    const int h = blockIdx.y, q0 = blockIdx.x * 64;
    const int tid = threadIdx.x, w = tid >> 6, l = tid & 63;
    const int lr = l & 15, lg = l >> 4;

    // Q fragments (padded buffers -> no guard; pad rows produce unused rows)
    bf16x8 qh[2], ql[2];
    {
        const size_t qoff = ((size_t)h * NSEQP + q0 + 16 * w + lr) * DH;
#pragma unroll
        for (int ks = 0; ks < 2; ++ks) {
            qh[ks] = *(const bf16x8*)&Qhi[qoff + 32 * ks + 8 * lg];
            ql[ks] = *(const bf16x8*)&Qlo[qoff + 32 * ks + 8 * lg];
        }
    }

    const bf16_t* Kbh = Khi + (size_t)h * NSEQP * DH;
    const bf16_t* Kbl = Klo + (size_t)h * NSEQP * DH;
    const bf16_t* Vb  = Vt  + (size_t)h * DH * NSEQP;

    f32x4 o[4] = {};
    float m[4], lsum[4];
#pragma unroll
    for (int r = 0; r < 4; ++r) { m[r] = -1e30f; lsum[r] = 0.f; }

    for (int j0 = 0; j0 < NSEQ; j0 += 64) {
        // ---- QK^T (split-3), K frags direct from global ----
        f32x4 s[4] = {};
        __builtin_amdgcn_s_setprio(1);
#pragma unroll
        for (int ct = 0; ct < 4; ++ct) {
            const size_t krow = (size_t)(j0 + 16 * ct + lr) * DH;
#pragma unroll
            for (int ks = 0; ks < 2; ++ks) {
                bf16x8 bh = *(const bf16x8*)&Kbh[krow + 32 * ks + 8 * lg];
                bf16x8 bl = *(const bf16x8*)&Kbl[krow + 32 * ks + 8 * lg];
                s[ct] = MFMA(ql[ks], bh, s[ct]);
                s[ct] = MFMA(qh[ks], bl, s[ct]);
                s[ct] = MFMA(qh[ks], bh, s[ct]);
            }
        }
        __builtin_amdgcn_s_setprio(0);
#pragma unroll
        for (int ct = 0; ct < 4; ++ct) {
            if (j0 + 16 * ct + lr >= NSEQ) {
                s[ct][0] = -1e30f; s[ct][1] = -1e30f;
                s[ct][2] = -1e30f; s[ct][3] = -1e30f;
            }
        }

        // ---- online softmax (rows q = 4*lg+reg; reduce over 16-lane group) ----
        float so[4];
#pragma unroll
        for (int reg = 0; reg < 4; ++reg) {
            float mt = fmaxf(fmaxf(s[0][reg], s[1][reg]), fmaxf(s[2][reg], s[3][reg]));
#pragma unroll
            for (int off = 1; off < 16; off <<= 1)
                mt = fmaxf(mt, __shfl_xor(mt, off));
            float mn = fmaxf(m[reg], mt);
            so[reg] = __expf(m[reg] - mn);
            m[reg] = mn;
            float psum = 0.f;
#pragma unroll
            for (int ct = 0; ct < 4; ++ct) {
                float pv = __expf(s[ct][reg] - mn);
                s[ct][reg] = pv;
                psum += pv;
            }
#pragma unroll
            for (int off = 1; off < 16; off <<= 1)
                psum += __shfl_xor(psum, off);
            lsum[reg] = lsum[reg] * so[reg] + psum;
        }

        // write P (wave-private LDS rows; in-wave RAW via lgkmcnt, no barrier)
#pragma unroll
        for (int ct = 0; ct < 4; ++ct)
#pragma unroll
            for (int reg = 0; reg < 4; ++reg)
                PS[w][(4 * lg + reg) * ASTRH + 16 * ct + lr] = (bf16_t)s[ct][reg];

        // rescale O accumulators
#pragma unroll
        for (int ctd = 0; ctd < 4; ++ctd)
#pragma unroll
            for (int reg = 0; reg < 4; ++reg)
                o[ctd][reg] *= so[reg];

        // ---- PV: P from LDS, V^T frags direct from global ----
        __builtin_amdgcn_s_setprio(1);
#pragma unroll
        for (int ks = 0; ks < 2; ++ks) {
            bf16x8 pa = *(const bf16x8*)&PS[w][lr * ASTRH + 32 * ks + 8 * lg];
#pragma unroll
            for (int ctd = 0; ctd < 4; ++ctd) {
                bf16x8 vb = *(const bf16x8*)&Vb[(size_t)(16 * ctd + lr) * NSEQP
                                                + j0 + 32 * ks + 8 * lg];
                o[ctd] = MFMA(pa, vb, o[ctd]);
            }
        }
        __builtin_amdgcn_s_setprio(0);
    }

    // ---- store O[seq][h*64+d] ----
#pragma unroll
    for (int ctd = 0; ctd < 4; ++ctd) {
#pragma unroll
        for (int reg = 0; reg < 4; ++reg) {
            const int seq = q0 + 16 * w + 4 * lg + reg;
            if (seq < NSEQ)
                O[(size_t)seq * DIM + h * DH + 16 * ctd + lr] = o[ctd][reg] / lsum[reg];
        }
    }
}

// ===========================================================================
// GEMM 2: out = O @ W_proj^T + b, split-3 bf16 MFMA. 64x64 tile, BK=32,
// 256 threads = 4 waves (2x2 of 32x32), double-buffered, T14 staging.
// ===========================================================================
__global__ __launch_bounds__(256) void gemm_proj(
    const float* __restrict__ A, const float* __restrict__ B,
    const float* __restrict__ bias, float* __restrict__ C)
{
    __shared__ bf16_t Ah[2][64*GSTR], Al[2][64*GSTR];
    __shared__ bf16_t Bh[2][64*GSTR], Bl[2][64*GSTR];

    const int tid = threadIdx.x;
    const int m0 = blockIdx.y * 64, n0 = blockIdx.x * 64;
    const int w = tid >> 6, l = tid & 63, lr = l & 15, lg = l >> 4;
    const int wrow = (w >> 1) * 32, wcol = (w & 1) * 32;
    const int sr = tid >> 2;          // 0..63
    const int sc = (tid & 3) * 8;

    const float* Arow = A + (size_t)(m0 + sr) * DIM + sc;
    const float* Brow = B + (size_t)(n0 + sr) * DIM + sc;
    const bool aok = (m0 + sr) < NSEQ;
    const float4 z4 = make_float4(0.f, 0.f, 0.f, 0.f);

    f32x4 acc[2][2] = {};
    float4 ra0, ra1, rb0, rb1;

#define LOADK(k0) do { \
        ra0 = aok ? *(const float4*)(Arow + (k0))     : z4; \
        ra1 = aok ? *(const float4*)(Arow + (k0) + 4) : z4; \
        rb0 = *(const float4*)(Brow + (k0)); \
        rb1 = *(const float4*)(Brow + (k0) + 4); } while (0)
#define STOREK(p) do { \
        Split8 sa = split8(ra0, ra1); \
        *(bf16x8*)&Ah[p][sr*GSTR + sc] = sa.h; \
        *(bf16x8*)&Al[p][sr*GSTR + sc] = sa.l; \
        Split8 sb = split8(rb0, rb1); \
        *(bf16x8*)&Bh[p][sr*GSTR + sc] = sb.h; \
        *(bf16x8*)&Bl[p][sr*GSTR + sc] = sb.l; } while (0)

    LOADK(0);
    STOREK(0);
    __syncthreads();

    int p = 0;
    for (int kt = 0; kt < 32; ++kt) {
        if (kt < 31) LOADK((kt + 1) * 32);

        bf16x8 ah[2], al[2];
#pragma unroll
        for (int rt = 0; rt < 2; ++rt) {
            ah[rt] = *(const bf16x8*)&Ah[p][(wrow + 16*rt + lr)*GSTR + lg*8];
            al[rt] = *(const bf16x8*)&Al[p][(wrow + 16*rt + lr)*GSTR + lg*8];
        }
#pragma unroll
        for (int ct = 0; ct < 2; ++ct) {
            bf16x8 bh = *(const bf16x8*)&Bh[p][(wcol + 16*ct + lr)*GSTR + lg*8];
            bf16x8 bl = *(const bf16x8*)&Bl[p][(wcol + 16*ct + lr)*GSTR + lg*8];
#pragma unroll
            for (int rt = 0; rt < 2; ++rt) {
                acc[rt][ct] = MFMA(al[rt], bh, acc[rt][ct]);
                acc[rt][ct] = MFMA(ah[rt], bl, acc[rt][ct]);
                acc[rt][ct] = MFMA(ah[rt], bh, acc[rt][ct]);
            }
        }

        if (kt < 31) STOREK(p ^ 1);
        __syncthreads();
        p ^= 1;
    }
#undef LOADK
#undef STOREK

#pragma unroll
    for (int ct = 0; ct < 2; ++ct) {
        const int n = n0 + wcol + 16 * ct + lr;
        const float bv = bias[n];
#pragma unroll
        for (int rt = 0; rt < 2; ++rt) {
#pragma unroll
            for (int reg = 0; reg < 4; ++reg) {
                const int seq = m0 + wrow + 16 * rt + 4 * lg + reg;
                if (seq < NSEQ)
                    C[(size_t)seq * DIM + n] = acc[rt][ct][reg] + bv;
            }
        }
    }
}

// ===========================================================================
extern "C" void kernel_launch(void* const* d_in, const int* in_sizes, int n_in,
                              void* d_out, int out_size, void* d_ws, size_t ws_size,
                              hipStream_t stream)
{
    const float* x     = (const float*)d_in[0];
    const float* rope  = (const float*)d_in[1];
    const float* Wqkv  = (const float*)d_in[2];
    const float* Wproj = (const float*)d_in[3];
    const float* bproj = (const float*)d_in[4];
    float* out = (float*)d_out;

    const size_t HSP = (size_t)NH * NSEQP * DH;   // 1,703,936 elems
    bf16_t* Qhi = (bf16_t*)d_ws;
    bf16_t* Qlo = Qhi + HSP;
    bf16_t* Khi = Qlo + HSP;
    bf16_t* Klo = Khi + HSP;
    bf16_t* Vt  = Klo + HSP;                      // [h][64][NSEQP]
    float*  O   = (float*)(Vt + HSP);             // [NSEQ][DIM]

    gemm_qkv<<<dim3(3 * DIM / 128, (NSEQ + 127) / 128), 512, 0, stream>>>(
        x, Wqkv, rope, Qhi, Qlo, Khi, Klo, Vt);

    attn_kernel<<<dim3(NSEQP / 64, NH), 256, 0, stream>>>(
        Qhi, Qlo, Khi, Klo, Vt, O);

    gemm_proj<<<dim3(DIM / 64, (NSEQ + 63) / 64), 256, 0, stream>>>(
        O, Wproj, bproj, out);
}

// Round 7
// 245.044 us; speedup vs baseline: 1.7431x; 1.7431x over previous
//
#include <hip/hip_runtime.h>
#include <hip/hip_bf16.h>

#define DIM    1024
#define NH     16
#define DH     64
#define NSEQ   1605
#define HWIN   1600
#define PREFIX 5
#define NSEQP  1664   // 13*128, padded M / padded seq
#define KX     3072   // extended K': [hi | seg1 | seg2] segments of 1024

typedef __bf16 bf16_t;
typedef bf16_t bf16x4 __attribute__((ext_vector_type(4)));
typedef bf16_t bf16x8 __attribute__((ext_vector_type(8)));
typedef float  f32x4  __attribute__((ext_vector_type(4)));
typedef unsigned short u16;

#define MFMA(a,b,c) __builtin_amdgcn_mfma_f32_16x16x32_bf16(a,b,c,0,0,0)

union BU { bf16_t b; u16 u; };

// ---------------------------------------------------------------------------
// global->LDS direct staging of a [ROWS][64-half] tile. LDS layout is linear
// [row][64]; the XOR chunk swizzle (chunk ^ (row&7)) is applied to the GLOBAL
// source address (rule: linear dest + inverse-swizzled source + swizzled read)
// so ds_read_b128 fragments are bank-conflict-free despite the 128B row stride.
// ---------------------------------------------------------------------------
template<int ROWS>
__device__ __forceinline__ void stage64(const bf16_t* __restrict__ seg,
                                        int row0, int ldk, int kin,
                                        bf16_t* lds, int tid)
{
    const int l = tid & 63, w = tid >> 6;
#pragma unroll
    for (int i = 0; i < ROWS / 32; ++i) {
        const int rb = i * 32 + w * 8;            // wave-uniform LDS row base
        const int r  = rb + (l >> 3);             // lane's tile row
        const int p  = l & 7;                     // physical 16B chunk
        const bf16_t* src = seg + (size_t)(row0 + r) * ldk + kin + ((p ^ (r & 7)) << 3);
        __builtin_amdgcn_global_load_lds(
            (const __attribute__((address_space(1))) void*)src,
            (__attribute__((address_space(3))) void*)(lds + rb * 64),
            16, 0, 0);
    }
}

// swizzled LDS fragment read: logical (row, 16B-chunk) of a [*][64] tile
__device__ __forceinline__ bf16x8 frag(const bf16_t* lds, int row, int ch) {
    return *(const bf16x8*)&lds[row * 64 + ((ch ^ (row & 7)) << 3)];
}

// ---------------------------------------------------------------------------
// prep: split fp32 inputs into hi/lo bf16 planes (one float4 per thread).
// x -> xh/xl [NSEQP][1024] (pad rows zero); Wqkv -> wqh/wql [3072][1024];
// Wproj -> wph/wpl [1024][1024].
// ---------------------------------------------------------------------------
#define NX4 (NSEQP * 256)
#define NQ4 (3072 * 256)
#define NP4 (1024 * 256)

__global__ __launch_bounds__(256) void prep_kernel(
    const float* __restrict__ x, const float* __restrict__ Wq,
    const float* __restrict__ Wp,
    bf16_t* __restrict__ xh, bf16_t* __restrict__ xl,
    bf16_t* __restrict__ wqh, bf16_t* __restrict__ wql,
    bf16_t* __restrict__ wph, bf16_t* __restrict__ wpl)
{
    const int i = blockIdx.x * 256 + threadIdx.x;
    if (i >= NX4 + NQ4 + NP4) return;
    float4 v = make_float4(0.f, 0.f, 0.f, 0.f);
    bf16_t *ph, *pl;
    size_t off;
    if (i < NX4) {
        if ((i >> 8) < NSEQ) v = ((const float4*)x)[i];
        ph = xh; pl = xl; off = (size_t)i * 4;
    } else if (i < NX4 + NQ4) {
        int j = i - NX4;
        v = ((const float4*)Wq)[j];
        ph = wqh; pl = wql; off = (size_t)j * 4;
    } else {
        int j = i - NX4 - NQ4;
        v = ((const float4*)Wp)[j];
        ph = wph; pl = wpl; off = (size_t)j * 4;
    }
    bf16_t h0 = (bf16_t)v.x, h1 = (bf16_t)v.y, h2 = (bf16_t)v.z, h3 = (bf16_t)v.w;
    bf16x4 hv = {h0, h1, h2, h3};
    bf16x4 lv = {(bf16_t)(v.x - (float)h0), (bf16_t)(v.y - (float)h1),
                 (bf16_t)(v.z - (float)h2), (bf16_t)(v.w - (float)h3)};
    *(bf16x4*)(ph + off) = hv;
    *(bf16x4*)(pl + off) = lv;
}

// ---------------------------------------------------------------------------
// GEMM 1: qkv = x @ W_qkv^T as a PLAIN bf16 GEMM over K'=3072 (split-3 via
// K-extension: A segs [xh, xl, xh], B segs [wqh, wqh, wql]). 128x128 tile,
// BK=64, 256 thr / 4 waves (2x2 of 64x64), global_load_lds staging.
// Epilogue: RoPE fused in registers, Q/K split hi/lo head-major, V^T bf16.
// ---------------------------------------------------------------------------
__global__ __launch_bounds__(256, 2) void gemm_qkv(
    const bf16_t* __restrict__ xh, const bf16_t* __restrict__ xl,
    const bf16_t* __restrict__ wqh, const bf16_t* __restrict__ wql,
    const float* __restrict__ rope,
    bf16_t* __restrict__ Qhi, bf16_t* __restrict__ Qlo,
    bf16_t* __restrict__ Khi, bf16_t* __restrict__ Klo,
    bf16_t* __restrict__ Vt)
{
    __shared__ bf16_t As[128 * 64];
    __shared__ bf16_t Bs[128 * 64];

    // bijective XCD swizzle (grid 24x13 = 312 = 39*8)
    const int lin = blockIdx.y * 24 + blockIdx.x;
    const int swz = (lin & 7) * 39 + (lin >> 3);
    const int m0 = (swz / 24) * 128, n0 = (swz % 24) * 128;

    const int tid = threadIdx.x;
    const int w = tid >> 6, l = tid & 63, lr = l & 15, lg = l >> 4;
    const int wr = (w >> 1) * 64, wc = (w & 1) * 64;

    f32x4 acc[4][4] = {};

    for (int kt = 0; kt < KX / 64; ++kt) {
        const int k0 = kt * 64, sg = k0 >> 10, kin = k0 & 1023;
        const bf16_t* Aseg = (sg == 1) ? xl : xh;
        const bf16_t* Bseg = (sg == 2) ? wql : wqh;
        stage64<128>(Aseg, m0, 1024, kin, As, tid);
        stage64<128>(Bseg, n0, 1024, kin, Bs, tid);
        __syncthreads();
#pragma unroll
        for (int ks = 0; ks < 2; ++ks) {
            bf16x8 a[4];
#pragma unroll
            for (int rt = 0; rt < 4; ++rt) a[rt] = frag(As, wr + 16 * rt + lr, ks * 4 + lg);
#pragma unroll
            for (int ct = 0; ct < 4; ++ct) {
                bf16x8 b = frag(Bs, wc + 16 * ct + lr, ks * 4 + lg);
#pragma unroll
                for (int rt = 0; rt < 4; ++rt)
                    acc[rt][ct] = MFMA(a[rt], b, acc[rt][ct]);
            }
        }
        __syncthreads();
    }

    // ---- epilogue: RoPE + split + head-major scatter ----
    const int which = n0 >> 10;               // 0=Q 1=K 2=V (tiles never straddle)
    const int cbase = (n0 & 1023) + wc;       // wave's 64-col span = one head
    const float qscale = (which == 0) ? 0.125f : 1.0f;
    const float* sinp = rope;
    const float* cosp = rope + (size_t)HWIN * DH;

#pragma unroll
    for (int ct = 0; ct < 4; ++ct) {
        const int col = cbase + 16 * ct + lr;
        const int hd = col >> 6, dd = col & 63;
#pragma unroll
        for (int rt = 0; rt < 4; ++rt) {
            const int sbase = m0 + wr + 16 * rt + 4 * lg;   // + reg
            if (sbase >= NSEQ) continue;
            if (which == 2) {
                size_t off = ((size_t)hd * DH + dd) * NSEQP + sbase;
                if (sbase + 3 < NSEQ) {
                    BU t0, t1, t2, t3;
                    t0.b = (bf16_t)acc[rt][ct][0]; t1.b = (bf16_t)acc[rt][ct][1];
                    t2.b = (bf16_t)acc[rt][ct][2]; t3.b = (bf16_t)acc[rt][ct][3];
                    *(ushort4*)((u16*)Vt + off) = make_ushort4(t0.u, t1.u, t2.u, t3.u);
                } else {
#pragma unroll
                    for (int reg = 0; reg < 4; ++reg)
                        if (sbase + reg < NSEQ)
                            Vt[off + reg] = (bf16_t)acc[rt][ct][reg];
                }
            } else {
#pragma unroll
                for (int reg = 0; reg < 4; ++reg) {
                    const int seq = sbase + reg;
                    if (seq >= NSEQ) continue;
                    float val = acc[rt][ct][reg] * qscale;
                    float o = val;
                    if (seq >= PREFIX) {
                        float partner = acc[rt][ct ^ 2][reg] * qscale;
                        float rot = (dd < 32) ? -partner : partner;
                        float sn = sinp[(size_t)(seq - PREFIX) * DH + dd];
                        float cs = cosp[(size_t)(seq - PREFIX) * DH + dd];
                        o = val * cs + rot * sn;
                    }
                    bf16_t hh = (bf16_t)o;
                    bf16_t ll = (bf16_t)(o - (float)hh);
                    size_t off = ((size_t)hd * NSEQP + seq) * DH + dd;
                    if (which == 0) { Qhi[off] = hh; Qlo[off] = ll; }
                    else            { Khi[off] = hh; Klo[off] = ll; }
                }
            }
        }
    }
}

// ---------------------------------------------------------------------------
// Flash attention: block = (head, 64-q tile), 4 waves of 16 q rows.
// Q hi/lo in registers; K hi/lo + V^T staged to LDS via global_load_lds
// (pure DMA, conflict-free swizzled reads); split-3 QK^T; online softmax;
// PV in bf16. Epilogue emits O as hi/lo bf16 (proj GEMM A-operand).
// ---------------------------------------------------------------------------
#define ASTRH 72

__global__ __launch_bounds__(256, 2) void attn_kernel(
    const bf16_t* __restrict__ Qhi, const bf16_t* __restrict__ Qlo,
    const bf16_t* __restrict__ Khi, const bf16_t* __restrict__ Klo,
    const bf16_t* __restrict__ Vt,
    bf16_t* __restrict__ Oh, bf16_t* __restrict__ Ol)
{
    __shared__ bf16_t Ksh[64 * 64], Ksl[64 * 64], Vsh[64 * 64];
    __shared__ bf16_t PS[4][16 * ASTRH];

    // bijective XCD swizzle (grid 26x16 = 416 = 52*8); contiguous q-tiles of
    // one head land on one XCD -> K/V L2 reuse.
    const int lin = blockIdx.y * 26 + blockIdx.x;
    const int swz = (lin & 7) * 52 + (lin >> 3);
    const int h = swz / 26, q0 = (swz % 26) * 64;

    const int tid = threadIdx.x, w = tid >> 6, l = tid & 63;
    const int lr = l & 15, lg = l >> 4;

    // Q fragments (held in registers; padded rows give discarded outputs)
    bf16x8 qh[2], ql[2];
    {
        const size_t qoff = ((size_t)h * NSEQP + q0 + 16 * w + lr) * DH;
#pragma unroll
        for (int ks = 0; ks < 2; ++ks) {
            qh[ks] = *(const bf16x8*)&Qhi[qoff + 32 * ks + 8 * lg];
            ql[ks] = *(const bf16x8*)&Qlo[qoff + 32 * ks + 8 * lg];
        }
    }

    const bf16_t* KbH = Khi + (size_t)h * NSEQP * DH;
    const bf16_t* KbL = Klo + (size_t)h * NSEQP * DH;
    const bf16_t* Vb  = Vt  + (size_t)h * DH * NSEQP;

    f32x4 o[4] = {};
    float m[4], lsum[4];
#pragma unroll
    for (int r = 0; r < 4; ++r) { m[r] = -1e30f; lsum[r] = 0.f; }

    for (int j0 = 0; j0 < NSEQ; j0 += 64) {
        stage64<64>(KbH, j0, 64, 0, Ksh, tid);
        stage64<64>(KbL, j0, 64, 0, Ksl, tid);
        stage64<64>(Vb, 0, NSEQP, j0, Vsh, tid);
        __syncthreads();

        // ---- QK^T (split-3) ----
        f32x4 s[4] = {};
        __builtin_amdgcn_s_setprio(1);
#pragma unroll
        for (int ct = 0; ct < 4; ++ct) {
#pragma unroll
            for (int ks = 0; ks < 2; ++ks) {
                bf16x8 bh = frag(Ksh, 16 * ct + lr, ks * 4 + lg);
                bf16x8 bl = frag(Ksl, 16 * ct + lr, ks * 4 + lg);
                s[ct] = MFMA(ql[ks], bh, s[ct]);
                s[ct] = MFMA(qh[ks], bl, s[ct]);
                s[ct] = MFMA(qh[ks], bh, s[ct]);
            }
        }
        __builtin_amdgcn_s_setprio(0);
#pragma unroll
        for (int ct = 0; ct < 4; ++ct) {
            if (j0 + 16 * ct + lr >= NSEQ) {
                s[ct][0] = -1e30f; s[ct][1] = -1e30f;
                s[ct][2] = -1e30f; s[ct][3] = -1e30f;
            }
        }

        // ---- online softmax (rows q = 4*lg+reg; reduce over 16-lane group) ----
        float so[4];
#pragma unroll
        for (int reg = 0; reg < 4; ++reg) {
            float mt = fmaxf(fmaxf(s[0][reg], s[1][reg]), fmaxf(s[2][reg], s[3][reg]));
#pragma unroll
            for (int off = 1; off < 16; off <<= 1)
                mt = fmaxf(mt, __shfl_xor(mt, off));
            float mn = fmaxf(m[reg], mt);
            so[reg] = __expf(m[reg] - mn);
            m[reg] = mn;
            float psum = 0.f;
#pragma unroll
            for (int ct = 0; ct < 4; ++ct) {
                float pv = __expf(s[ct][reg] - mn);
                s[ct][reg] = pv;
                psum += pv;
            }
#pragma unroll
            for (int off = 1; off < 16; off <<= 1)
                psum += __shfl_xor(psum, off);
            lsum[reg] = lsum[reg] * so[reg] + psum;
        }

        // write P (wave-private LDS rows; in-wave RAW ordered by lgkmcnt)
#pragma unroll
        for (int ct = 0; ct < 4; ++ct)
#pragma unroll
            for (int reg = 0; reg < 4; ++reg)
                PS[w][(4 * lg + reg) * ASTRH + 16 * ct + lr] = (bf16_t)s[ct][reg];

        // rescale O accumulators
#pragma unroll
        for (int ctd = 0; ctd < 4; ++ctd)
#pragma unroll
            for (int reg = 0; reg < 4; ++reg)
                o[ctd][reg] *= so[reg];

        // ---- PV ----
        __builtin_amdgcn_s_setprio(1);
#pragma unroll
        for (int ks = 0; ks < 2; ++ks) {
            bf16x8 pa = *(const bf16x8*)&PS[w][lr * ASTRH + 32 * ks + 8 * lg];
#pragma unroll
            for (int ctd = 0; ctd < 4; ++ctd) {
                bf16x8 vb = frag(Vsh, 16 * ctd + lr, ks * 4 + lg);
                o[ctd] = MFMA(pa, vb, o[ctd]);
            }
        }
        __builtin_amdgcn_s_setprio(0);
        __syncthreads();   // protect K/V tiles before next stage
    }

    // ---- epilogue: O -> hi/lo bf16 [seq][DIM] ----
#pragma unroll
    for (int ctd = 0; ctd < 4; ++ctd) {
#pragma unroll
        for (int reg = 0; reg < 4; ++reg) {
            const int seq = q0 + 16 * w + 4 * lg + reg;
            if (seq < NSEQ) {
                float ov = o[ctd][reg] / lsum[reg];
                bf16_t hi = (bf16_t)ov;
                bf16_t lo = (bf16_t)(ov - (float)hi);
                size_t oo = (size_t)seq * DIM + h * DH + 16 * ctd + lr;
                Oh[oo] = hi; Ol[oo] = lo;
            }
        }
    }
}

// ---------------------------------------------------------------------------
// GEMM 2: out = O @ W_proj^T + b as plain bf16 GEMM over K'=3072
// (A segs [oh, ol, oh], B segs [wph, wph, wpl]). 64x128 tile, BK=64,
// 256 thr / 4 waves (2x2 of 32x64).
// ---------------------------------------------------------------------------
__global__ __launch_bounds__(256, 2) void gemm_proj(
    const bf16_t* __restrict__ oh, const bf16_t* __restrict__ ol,
    const bf16_t* __restrict__ wph, const bf16_t* __restrict__ wpl,
    const float* __restrict__ bias, float* __restrict__ C)
{
    __shared__ bf16_t As[64 * 64];
    __shared__ bf16_t Bs[128 * 64];

    // bijective XCD swizzle (grid 8x26 = 208 = 26*8)
    const int lin = blockIdx.y * 8 + blockIdx.x;
    const int swz = (lin & 7) * 26 + (lin >> 3);
    const int m0 = (swz / 8) * 64, n0 = (swz % 8) * 128;

    const int tid = threadIdx.x;
    const int w = tid >> 6, l = tid & 63, lr = l & 15, lg = l >> 4;
    const int wr = (w >> 1) * 32, wc = (w & 1) * 64;

    f32x4 acc[2][4] = {};

    for (int kt = 0; kt < KX / 64; ++kt) {
        const int k0 = kt * 64, sg = k0 >> 10, kin = k0 & 1023;
        const bf16_t* Aseg = (sg == 1) ? ol : oh;
        const bf16_t* Bseg = (sg == 2) ? wpl : wph;
        stage64<64>(Aseg, m0, 1024, kin, As, tid);
        stage64<128>(Bseg, n0, 1024, kin, Bs, tid);
        __syncthreads();
#pragma unroll
        for (int ks = 0; ks < 2; ++ks) {
            bf16x8 a[2];
#pragma unroll
            for (int rt = 0; rt < 2; ++rt) a[rt] = frag(As, wr + 16 * rt + lr, ks * 4 + lg);
#pragma unroll
            for (int ct = 0; ct < 4; ++ct) {
                bf16x8 b = frag(Bs, wc + 16 * ct + lr, ks * 4 + lg);
#pragma unroll
                for (int rt = 0; rt < 2; ++rt)
                    acc[rt][ct] = MFMA(a[rt], b, acc[rt][ct]);
            }
        }
        __syncthreads();
    }

#pragma unroll
    for (int ct = 0; ct < 4; ++ct) {
        const int n = n0 + wc + 16 * ct + lr;
        const float bv = bias[n];
#pragma unroll
        for (int rt = 0; rt < 2; ++rt) {
#pragma unroll
            for (int reg = 0; reg < 4; ++reg) {
                const int seq = m0 + wr + 16 * rt + 4 * lg + reg;
                if (seq < NSEQ)
                    C[(size_t)seq * DIM + n] = acc[rt][ct][reg] + bv;
            }
        }
    }
}

// ===========================================================================
extern "C" void kernel_launch(void* const* d_in, const int* in_sizes, int n_in,
                              void* d_out, int out_size, void* d_ws, size_t ws_size,
                              hipStream_t stream)
{
    const float* x     = (const float*)d_in[0];
    const float* rope  = (const float*)d_in[1];
    const float* Wqkv  = (const float*)d_in[2];
    const float* Wproj = (const float*)d_in[3];
    const float* bproj = (const float*)d_in[4];
    float* out = (float*)d_out;

    // workspace layout (halves). Oh/Ol alias xh/xl: x is dead after gemm_qkv.
    const size_t XE  = (size_t)NSEQP * 1024;   // 1,703,936
    const size_t WQE = (size_t)3072 * 1024;
    const size_t WPE = (size_t)1024 * 1024;
    const size_t HSE = (size_t)NH * NSEQP * DH;

    bf16_t* p = (bf16_t*)d_ws;
    bf16_t* xh  = p; p += XE;
    bf16_t* xl  = p; p += XE;
    bf16_t* wqh = p; p += WQE;
    bf16_t* wql = p; p += WQE;
    bf16_t* wph = p; p += WPE;
    bf16_t* wpl = p; p += WPE;
    bf16_t* Qhi = p; p += HSE;
    bf16_t* Qlo = p; p += HSE;
    bf16_t* Khi = p; p += HSE;
    bf16_t* Klo = p; p += HSE;
    bf16_t* Vt  = p; p += HSE;
    bf16_t* Oh  = xh;     // alias (x consumed by gemm_qkv before attn runs)
    bf16_t* Ol  = xl;

    const int PTOT = NX4 + NQ4 + NP4;
    prep_kernel<<<(PTOT + 255) / 256, 256, 0, stream>>>(
        x, Wqkv, Wproj, xh, xl, wqh, wql, wph, wpl);

    gemm_qkv<<<dim3(KX / 128, NSEQP / 128), 256, 0, stream>>>(
        xh, xl, wqh, wql, rope, Qhi, Qlo, Khi, Klo, Vt);

    attn_kernel<<<dim3(NSEQP / 64, NH), 256, 0, stream>>>(
        Qhi, Qlo, Khi, Klo, Vt, Oh, Ol);

    gemm_proj<<<dim3(DIM / 128, NSEQP / 64), 256, 0, stream>>>(
        Oh, Ol, wph, wpl, bproj, out);
}

// Round 9
// 224.639 us; speedup vs baseline: 1.9015x; 1.0908x over previous
//
#include <hip/hip_runtime.h>
#include <hip/hip_bf16.h>

#define DIM    1024
#define NH     16
#define DH     64
#define NSEQ   1605
#define HWIN   1600
#define PREFIX 5
#define NSEQP  1664   // 26*64, padded M / padded seq
#define KX     3072   // extended K': split-3 as [hi | lo*Bh | hi*Bl] segments

typedef __bf16 bf16_t;
typedef bf16_t bf16x4 __attribute__((ext_vector_type(4)));
typedef bf16_t bf16x8 __attribute__((ext_vector_type(8)));
typedef float  f32x4  __attribute__((ext_vector_type(4)));
typedef unsigned short u16;

#define MFMA(a,b,c) __builtin_amdgcn_mfma_f32_16x16x32_bf16(a,b,c,0,0,0)

union BU { bf16_t b; u16 u; };

// ---------------------------------------------------------------------------
// global->LDS staging of [ROWS][64-half] tile: linear LDS dest, XOR chunk
// swizzle applied to the GLOBAL source, swizzled read via frag() below.
// ---------------------------------------------------------------------------
template<int ROWS>
__device__ __forceinline__ void stage64(const bf16_t* __restrict__ seg,
                                        int row0, int ldk, int kin,
                                        bf16_t* lds, int tid)
{
    const int l = tid & 63, w = tid >> 6;
#pragma unroll
    for (int i = 0; i < ROWS / 32; ++i) {
        const int rb = i * 32 + w * 8;            // wave-uniform LDS row base
        const int r  = rb + (l >> 3);             // lane's tile row
        const int p  = l & 7;                     // physical 16B chunk
        const bf16_t* src = seg + (size_t)(row0 + r) * ldk + kin + ((p ^ (r & 7)) << 3);
        __builtin_amdgcn_global_load_lds(
            (const __attribute__((address_space(1))) void*)src,
            (__attribute__((address_space(3))) void*)(lds + rb * 64),
            16, 0, 0);
    }
}

__device__ __forceinline__ bf16x8 frag(const bf16_t* lds, int row, int ch) {
    return *(const bf16x8*)&lds[row * 64 + ((ch ^ (row & 7)) << 3)];
}

// ---------------------------------------------------------------------------
// prep: split fp32 inputs into hi/lo bf16 planes.
// ---------------------------------------------------------------------------
#define NX4 (NSEQP * 256)
#define NQ4 (3072 * 256)
#define NP4 (1024 * 256)

__global__ __launch_bounds__(256) void prep_kernel(
    const float* __restrict__ x, const float* __restrict__ Wq,
    const float* __restrict__ Wp,
    bf16_t* __restrict__ xh, bf16_t* __restrict__ xl,
    bf16_t* __restrict__ wqh, bf16_t* __restrict__ wql,
    bf16_t* __restrict__ wph, bf16_t* __restrict__ wpl)
{
    const int i = blockIdx.x * 256 + threadIdx.x;
    if (i >= NX4 + NQ4 + NP4) return;
    float4 v = make_float4(0.f, 0.f, 0.f, 0.f);
    bf16_t *ph, *pl;
    size_t off;
    if (i < NX4) {
        if ((i >> 8) < NSEQ) v = ((const float4*)x)[i];
        ph = xh; pl = xl; off = (size_t)i * 4;
    } else if (i < NX4 + NQ4) {
        int j = i - NX4;
        v = ((const float4*)Wq)[j];
        ph = wqh; pl = wql; off = (size_t)j * 4;
    } else {
        int j = i - NX4 - NQ4;
        v = ((const float4*)Wp)[j];
        ph = wph; pl = wpl; off = (size_t)j * 4;
    }
    bf16_t h0 = (bf16_t)v.x, h1 = (bf16_t)v.y, h2 = (bf16_t)v.z, h3 = (bf16_t)v.w;
    bf16x4 hv = {h0, h1, h2, h3};
    bf16x4 lv = {(bf16_t)(v.x - (float)h0), (bf16_t)(v.y - (float)h1),
                 (bf16_t)(v.z - (float)h2), (bf16_t)(v.w - (float)h3)};
    *(bf16x4*)(ph + off) = hv;
    *(bf16x4*)(pl + off) = lv;
}

// ---------------------------------------------------------------------------
// GEMM 1: qkv = x @ W_qkv^T, plain bf16 GEMM over K'=3072.
// 64x128 tile, BK=64, 4 waves (2x2 of 32x64), 2-phase double-buffered LDS.
// Grid 24x26 = 624; XCD column-band swizzle. RoPE/split/V^T fused epilogue.
// ---------------------------------------------------------------------------
__global__ __launch_bounds__(256, 2) void gemm_qkv(
    const bf16_t* __restrict__ xh, const bf16_t* __restrict__ xl,
    const bf16_t* __restrict__ wqh, const bf16_t* __restrict__ wql,
    const float* __restrict__ rope,
    bf16_t* __restrict__ Qhi, bf16_t* __restrict__ Qlo,
    bf16_t* __restrict__ Khi, bf16_t* __restrict__ Klo,
    bf16_t* __restrict__ Vt)
{
    __shared__ bf16_t As[2][64 * 64];
    __shared__ bf16_t Bs[2][128 * 64];

    // XCD swizzle: each XCD owns 3 N-tiles x all 26 M-tiles (624 = 8*26*3)
    const int lin = blockIdx.y * 24 + blockIdx.x;
    const int xcd = lin & 7, idx = lin >> 3;        // idx 0..77
    const int m0 = (idx / 3) * 64;
    const int n0 = (xcd * 3 + idx % 3) * 128;

    const int tid = threadIdx.x;
    const int w = tid >> 6, l = tid & 63, lr = l & 15, lg = l >> 4;
    const int wr = (w >> 1) * 32, wc = (w & 1) * 64;

    f32x4 acc[2][4] = {};

    auto stage = [&](int buf, int kt) {
        const int k0 = kt * 64, sg = k0 >> 10, kin = k0 & 1023;
        const bf16_t* Aseg = (sg == 1) ? xl : xh;
        const bf16_t* Bseg = (sg == 2) ? wql : wqh;
        stage64<64>(Aseg, m0, 1024, kin, As[buf], tid);
        stage64<128>(Bseg, n0, 1024, kin, Bs[buf], tid);
    };

    stage(0, 0);
    __syncthreads();
    int cur = 0;
    for (int kt = 0; kt < KX / 64; ++kt) {
        if (kt + 1 < KX / 64) stage(cur ^ 1, kt + 1);   // prefetch next tile
#pragma unroll
        for (int ks = 0; ks < 2; ++ks) {
            bf16x8 a[2];
#pragma unroll
            for (int rt = 0; rt < 2; ++rt) a[rt] = frag(As[cur], wr + 16 * rt + lr, ks * 4 + lg);
#pragma unroll
            for (int ct = 0; ct < 4; ++ct) {
                bf16x8 b = frag(Bs[cur], wc + 16 * ct + lr, ks * 4 + lg);
#pragma unroll
                for (int rt = 0; rt < 2; ++rt)
                    acc[rt][ct] = MFMA(a[rt], b, acc[rt][ct]);
            }
        }
        __syncthreads();   // drains prefetch (vmcnt) + protects cur for restage
        cur ^= 1;
    }

    // ---- epilogue: RoPE + split + head-major scatter ----
    const int which = n0 >> 10;               // 0=Q 1=K 2=V
    const int cbase = (n0 & 1023) + wc;       // wave's 64-col span = one head
    const float qscale = (which == 0) ? 0.125f : 1.0f;
    const float* sinp = rope;
    const float* cosp = rope + (size_t)HWIN * DH;

#pragma unroll
    for (int ct = 0; ct < 4; ++ct) {
        const int col = cbase + 16 * ct + lr;
        const int hd = col >> 6, dd = col & 63;
#pragma unroll
        for (int rt = 0; rt < 2; ++rt) {
            const int sbase = m0 + wr + 16 * rt + 4 * lg;   // + reg
            if (sbase >= NSEQ) continue;
            if (which == 2) {
                size_t off = ((size_t)hd * DH + dd) * NSEQP + sbase;
                if (sbase + 3 < NSEQ) {
                    BU t0, t1, t2, t3;
                    t0.b = (bf16_t)acc[rt][ct][0]; t1.b = (bf16_t)acc[rt][ct][1];
                    t2.b = (bf16_t)acc[rt][ct][2]; t3.b = (bf16_t)acc[rt][ct][3];
                    *(ushort4*)((u16*)Vt + off) = make_ushort4(t0.u, t1.u, t2.u, t3.u);
                } else {
#pragma unroll
                    for (int reg = 0; reg < 4; ++reg)
                        if (sbase + reg < NSEQ)
                            Vt[off + reg] = (bf16_t)acc[rt][ct][reg];
                }
            } else {
#pragma unroll
                for (int reg = 0; reg < 4; ++reg) {
                    const int seq = sbase + reg;
                    if (seq >= NSEQ) continue;
                    float val = acc[rt][ct][reg] * qscale;
                    float o = val;
                    if (seq >= PREFIX) {
                        float partner = acc[rt][ct ^ 2][reg] * qscale;
                        float rot = (dd < 32) ? -partner : partner;
                        float sn = sinp[(size_t)(seq - PREFIX) * DH + dd];
                        float cs = cosp[(size_t)(seq - PREFIX) * DH + dd];
                        o = val * cs + rot * sn;
                    }
                    bf16_t hh = (bf16_t)o;
                    bf16_t ll = (bf16_t)(o - (float)hh);
                    size_t off = ((size_t)hd * NSEQP + seq) * DH + dd;
                    if (which == 0) { Qhi[off] = hh; Qlo[off] = ll; }
                    else            { Khi[off] = hh; Klo[off] = ll; }
                }
            }
        }
    }
}

// ---------------------------------------------------------------------------
// Flash attention: block = (head, 64-q tile), 4 waves of 16 q rows.
// 2-phase double-buffered K/V staging, ONE barrier per tile. Q in registers;
// split-3 QK^T; online softmax; PV bf16; O emitted as hi/lo bf16.
// ---------------------------------------------------------------------------
#define ASTRH 72
#define NJT   (NSEQP / 64)   // 26

__global__ __launch_bounds__(256, 2) void attn_kernel(
    const bf16_t* __restrict__ Qhi, const bf16_t* __restrict__ Qlo,
    const bf16_t* __restrict__ Khi, const bf16_t* __restrict__ Klo,
    const bf16_t* __restrict__ Vt,
    bf16_t* __restrict__ Oh, bf16_t* __restrict__ Ol)
{
    __shared__ bf16_t Ksh[2][64 * 64], Ksl[2][64 * 64], Vsh[2][64 * 64];
    __shared__ bf16_t PS[4][16 * ASTRH];

    // XCD swizzle: 2 heads per XCD (416 = 8*2*26) -> K/V L2-resident
    const int lin = blockIdx.y * 26 + blockIdx.x;
    const int xcd = lin & 7, idx = lin >> 3;        // idx 0..51
    const int h = 2 * xcd + idx / 26;
    const int q0 = (idx % 26) * 64;

    const int tid = threadIdx.x, w = tid >> 6, l = tid & 63;
    const int lr = l & 15, lg = l >> 4;

    bf16x8 qh[2], ql[2];
    {
        const size_t qoff = ((size_t)h * NSEQP + q0 + 16 * w + lr) * DH;
#pragma unroll
        for (int ks = 0; ks < 2; ++ks) {
            qh[ks] = *(const bf16x8*)&Qhi[qoff + 32 * ks + 8 * lg];
            ql[ks] = *(const bf16x8*)&Qlo[qoff + 32 * ks + 8 * lg];
        }
    }

    const bf16_t* KbH = Khi + (size_t)h * NSEQP * DH;
    const bf16_t* KbL = Klo + (size_t)h * NSEQP * DH;
    const bf16_t* Vb  = Vt  + (size_t)h * DH * NSEQP;

    f32x4 o[4] = {};
    float m[4], lsum[4];
#pragma unroll
    for (int r = 0; r < 4; ++r) { m[r] = -1e30f; lsum[r] = 0.f; }

    auto stage_kv = [&](int buf, int jt) {
        const int j0 = jt * 64;
        stage64<64>(KbH, j0, 64, 0, Ksh[buf], tid);
        stage64<64>(KbL, j0, 64, 0, Ksl[buf], tid);
        stage64<64>(Vb, 0, NSEQP, j0, Vsh[buf], tid);
    };

    stage_kv(0, 0);
    __syncthreads();
    int cur = 0;
    for (int jt = 0; jt < NJT; ++jt) {
        const int j0 = jt * 64;
        if (jt + 1 < NJT) stage_kv(cur ^ 1, jt + 1);   // prefetch next tile

        // ---- QK^T (split-3) ----
        f32x4 s[4] = {};
        __builtin_amdgcn_s_setprio(1);
#pragma unroll
        for (int ct = 0; ct < 4; ++ct) {
#pragma unroll
            for (int ks = 0; ks < 2; ++ks) {
                bf16x8 bh = frag(Ksh[cur], 16 * ct + lr, ks * 4 + lg);
                bf16x8 bl = frag(Ksl[cur], 16 * ct + lr, ks * 4 + lg);
                s[ct] = MFMA(ql[ks], bh, s[ct]);
                s[ct] = MFMA(qh[ks], bl, s[ct]);
                s[ct] = MFMA(qh[ks], bh, s[ct]);
            }
        }
        __builtin_amdgcn_s_setprio(0);
#pragma unroll
        for (int ct = 0; ct < 4; ++ct) {
            if (j0 + 16 * ct + lr >= NSEQ) {
                s[ct][0] = -1e30f; s[ct][1] = -1e30f;
                s[ct][2] = -1e30f; s[ct][3] = -1e30f;
            }
        }

        // ---- online softmax ----
        float so[4];
#pragma unroll
        for (int reg = 0; reg < 4; ++reg) {
            float mt = fmaxf(fmaxf(s[0][reg], s[1][reg]), fmaxf(s[2][reg], s[3][reg]));
#pragma unroll
            for (int off = 1; off < 16; off <<= 1)
                mt = fmaxf(mt, __shfl_xor(mt, off));
            float mn = fmaxf(m[reg], mt);
            so[reg] = __expf(m[reg] - mn);
            m[reg] = mn;
            float psum = 0.f;
#pragma unroll
            for (int ct = 0; ct < 4; ++ct) {
                float pv = __expf(s[ct][reg] - mn);
                s[ct][reg] = pv;
                psum += pv;
            }
#pragma unroll
            for (int off = 1; off < 16; off <<= 1)
                psum += __shfl_xor(psum, off);
            lsum[reg] = lsum[reg] * so[reg] + psum;
        }

        // write P (wave-private rows; in-wave RAW ordered by lgkmcnt)
#pragma unroll
        for (int ct = 0; ct < 4; ++ct)
#pragma unroll
            for (int reg = 0; reg < 4; ++reg)
                PS[w][(4 * lg + reg) * ASTRH + 16 * ct + lr] = (bf16_t)s[ct][reg];

#pragma unroll
        for (int ctd = 0; ctd < 4; ++ctd)
#pragma unroll
            for (int reg = 0; reg < 4; ++reg)
                o[ctd][reg] *= so[reg];

        // ---- PV ----
        __builtin_amdgcn_s_setprio(1);
#pragma unroll
        for (int ks = 0; ks < 2; ++ks) {
            bf16x8 pa = *(const bf16x8*)&PS[w][lr * ASTRH + 32 * ks + 8 * lg];
#pragma unroll
            for (int ctd = 0; ctd < 4; ++ctd) {
                bf16x8 vb = frag(Vsh[cur], 16 * ctd + lr, ks * 4 + lg);
                o[ctd] = MFMA(pa, vb, o[ctd]);
            }
        }
        __builtin_amdgcn_s_setprio(0);

        __syncthreads();   // drains prefetch + protects cur before restage
        cur ^= 1;
    }

    // ---- epilogue: O -> hi/lo bf16 [seq][DIM] ----
#pragma unroll
    for (int ctd = 0; ctd < 4; ++ctd) {
#pragma unroll
        for (int reg = 0; reg < 4; ++reg) {
            const int seq = q0 + 16 * w + 4 * lg + reg;
            if (seq < NSEQ) {
                float ov = o[ctd][reg] / lsum[reg];
                bf16_t hi = (bf16_t)ov;
                bf16_t lo = (bf16_t)(ov - (float)hi);
                size_t oo = (size_t)seq * DIM + h * DH + 16 * ctd + lr;
                Oh[oo] = hi; Ol[oo] = lo;
            }
        }
    }
}

// ---------------------------------------------------------------------------
// GEMM 2: out = O @ W_proj^T + b over K'=3072. 64x64 tile, BK=64, 4 waves
// (2x2 of 32x32), 2-phase double-buffered. Grid 16x26 = 416.
// ---------------------------------------------------------------------------
__global__ __launch_bounds__(256, 2) void gemm_proj(
    const bf16_t* __restrict__ oh, const bf16_t* __restrict__ ol,
    const bf16_t* __restrict__ wph, const bf16_t* __restrict__ wpl,
    const float* __restrict__ bias, float* __restrict__ C)
{
    __shared__ bf16_t As[2][64 * 64];
    __shared__ bf16_t Bs[2][64 * 64];

    // XCD swizzle: 2 N-tiles per XCD x all 26 M (416 = 8*26*2)
    const int lin = blockIdx.y * 16 + blockIdx.x;
    const int xcd = lin & 7, idx = lin >> 3;        // idx 0..51
    const int m0 = (idx >> 1) * 64;
    const int n0 = ((xcd << 1) | (idx & 1)) * 64;

    const int tid = threadIdx.x;
    const int w = tid >> 6, l = tid & 63, lr = l & 15, lg = l >> 4;
    const int wr = (w >> 1) * 32, wc = (w & 1) * 32;

    f32x4 acc[2][2] = {};

    auto stage = [&](int buf, int kt) {
        const int k0 = kt * 64, sg = k0 >> 10, kin = k0 & 1023;
        const bf16_t* Aseg = (sg == 1) ? ol : oh;
        const bf16_t* Bseg = (sg == 2) ? wpl : wph;
        stage64<64>(Aseg, m0, 1024, kin, As[buf], tid);
        stage64<64>(Bseg, n0, 1024, kin, Bs[buf], tid);
    };

    stage(0, 0);
    __syncthreads();
    int cur = 0;
    for (int kt = 0; kt < KX / 64; ++kt) {
        if (kt + 1 < KX / 64) stage(cur ^ 1, kt + 1);
#pragma unroll
        for (int ks = 0; ks < 2; ++ks) {
            bf16x8 a[2];
#pragma unroll
            for (int rt = 0; rt < 2; ++rt) a[rt] = frag(As[cur], wr + 16 * rt + lr, ks * 4 + lg);
#pragma unroll
            for (int ct = 0; ct < 2; ++ct) {
                bf16x8 b = frag(Bs[cur], wc + 16 * ct + lr, ks * 4 + lg);
#pragma unroll
                for (int rt = 0; rt < 2; ++rt)
                    acc[rt][ct] = MFMA(a[rt], b, acc[rt][ct]);
            }
        }
        __syncthreads();
        cur ^= 1;
    }

#pragma unroll
    for (int ct = 0; ct < 2; ++ct) {
        const int n = n0 + wc + 16 * ct + lr;
        const float bv = bias[n];
#pragma unroll
        for (int rt = 0; rt < 2; ++rt) {
#pragma unroll
            for (int reg = 0; reg < 4; ++reg) {
                const int seq = m0 + wr + 16 * rt + 4 * lg + reg;
                if (seq < NSEQ)
                    C[(size_t)seq * DIM + n] = acc[rt][ct][reg] + bv;
            }
        }
    }
}

// ===========================================================================
extern "C" void kernel_launch(void* const* d_in, const int* in_sizes, int n_in,
                              void* d_out, int out_size, void* d_ws, size_t ws_size,
                              hipStream_t stream)
{
    const float* x     = (const float*)d_in[0];
    const float* rope  = (const float*)d_in[1];
    const float* Wqkv  = (const float*)d_in[2];
    const float* Wproj = (const float*)d_in[3];
    const float* bproj = (const float*)d_in[4];
    float* out = (float*)d_out;

    const size_t XE  = (size_t)NSEQP * 1024;
    const size_t WQE = (size_t)3072 * 1024;
    const size_t WPE = (size_t)1024 * 1024;
    const size_t HSE = (size_t)NH * NSEQP * DH;

    bf16_t* p = (bf16_t*)d_ws;
    bf16_t* xh  = p; p += XE;
    bf16_t* xl  = p; p += XE;
    bf16_t* wqh = p; p += WQE;
    bf16_t* wql = p; p += WQE;
    bf16_t* wph = p; p += WPE;
    bf16_t* wpl = p; p += WPE;
    bf16_t* Qhi = p; p += HSE;
    bf16_t* Qlo = p; p += HSE;
    bf16_t* Khi = p; p += HSE;
    bf16_t* Klo = p; p += HSE;
    bf16_t* Vt  = p; p += HSE;
    bf16_t* Oh  = xh;     // alias: x consumed by gemm_qkv before attn runs
    bf16_t* Ol  = xl;

    const int PTOT = NX4 + NQ4 + NP4;
    prep_kernel<<<(PTOT + 255) / 256, 256, 0, stream>>>(
        x, Wqkv, Wproj, xh, xl, wqh, wql, wph, wpl);

    gemm_qkv<<<dim3(24, NSEQP / 64), 256, 0, stream>>>(
        xh, xl, wqh, wql, rope, Qhi, Qlo, Khi, Klo, Vt);

    attn_kernel<<<dim3(26, NH), 256, 0, stream>>>(
        Qhi, Qlo, Khi, Klo, Vt, Oh, Ol);

    gemm_proj<<<dim3(16, NSEQP / 64), 256, 0, stream>>>(
        Oh, Ol, wph, wpl, bproj, out);
}